// Round 5
// baseline (586.524 us; speedup 1.0000x reference)
//
#include <hip/hip_runtime.h>
#include <math.h>

#define EPS_  2.220446049250313e-16f

using bf16x8 = __attribute__((ext_vector_type(8))) short;
using f32x4  = __attribute__((ext_vector_type(4))) float;

__device__ __forceinline__ float gelu_exact(float x) {
    return 0.5f * x * (1.0f + erff(x * 0.70710678118654752f));
}

__device__ __forceinline__ unsigned short f2bf(float f) {
    unsigned u = __builtin_bit_cast(unsigned, f);
    u += 0x7FFF + ((u >> 16) & 1);              // RNE
    return (unsigned short)(u >> 16);
}

__device__ __forceinline__ bf16x8 pack8(float4 a, float4 b) {
    bf16x8 r;
    r[0] = (short)f2bf(a.x); r[1] = (short)f2bf(a.y);
    r[2] = (short)f2bf(a.z); r[3] = (short)f2bf(a.w);
    r[4] = (short)f2bf(b.x); r[5] = (short)f2bf(b.y);
    r[6] = (short)f2bf(b.z); r[7] = (short)f2bf(b.w);
    return r;
}

#define MFMA(a, b, c) __builtin_amdgcn_mfma_f32_16x16x32_bf16(a, b, c, 0, 0, 0)

// ---------------------------------------------------------------------------
// K0: convert all weights to bf16 MFMA B-fragment buffers (unchanged, passing).
// Ranges: conv1 32 tiles [0,2048); conv2 512 tiles [2048,34816);
//         fc 4096 tiles [34816,296960); experts 3072 tiles [296960,493568).
// ---------------------------------------------------------------------------
__global__ __launch_bounds__(256) void k_prep(
        const float* __restrict__ w1, const float* __restrict__ w2,
        const float* __restrict__ fcw, const float* __restrict__ ew,
        unsigned short* __restrict__ frag1, unsigned short* __restrict__ frag2,
        unsigned short* __restrict__ fragF, unsigned short* __restrict__ fragE) {
    int t = blockIdx.x * 256 + threadIdx.x;
    int lane = t & 63, col = lane & 15, grp = (lane >> 4) & 3;
    bf16x8 r;
    if (t < 2048) {                              // conv1: k=kh*64+kw*16+c, N=64
        int tile = t >> 6, nt = tile >> 3, ki = tile & 7;
        int n = nt * 16 + col;
        #pragma unroll
        for (int j = 0; j < 8; ++j) {
            int k = ki * 32 + grp * 8 + j;
            int kh = k >> 6, kw = (k >> 4) & 3, c = k & 15;
            r[j] = (short)f2bf(w1[((n * 16 + c) * 4 + kh) * 4 + kw]);
        }
        ((bf16x8*)frag1)[t] = r;
    } else if (t < 34816) {                      // conv2: k=kh*256+kw*64+c, N=256
        int u = t - 2048;
        int tile = u >> 6, nt = tile >> 5, kk = tile & 31;
        int n = nt * 16 + col;
        #pragma unroll
        for (int j = 0; j < 8; ++j) {
            int k = kk * 32 + grp * 8 + j;
            int kh = k >> 8, kw = (k >> 6) & 3, c = k & 63;
            r[j] = (short)f2bf(w2[((n * 64 + c) * 4 + kh) * 4 + kw]);
        }
        ((bf16x8*)frag2)[u] = r;
    } else if (t < 296960) {                     // fc: row-major [k][n]
        int u = t - 34816;
        int tile = u >> 6, nt = tile >> 7, kk = tile & 127;
        int n = nt * 16 + col;
        #pragma unroll
        for (int j = 0; j < 8; ++j) {
            int k = kk * 32 + grp * 8 + j;
            r[j] = (short)f2bf(fcw[(size_t)k * 512 + n]);
        }
        ((bf16x8*)fragF)[u] = r;
    } else if (t < 493568) {                     // experts: [e][k][n]
        int u = t - 296960;
        int tile = u >> 6, e = tile >> 9, rem = tile & 511;
        int nt = rem >> 4, kk = rem & 15;
        int n = nt * 16 + col;
        #pragma unroll
        for (int j = 0; j < 8; ++j) {
            int k = kk * 32 + grp * 8 + j;
            r[j] = (short)f2bf(ew[((size_t)e * 512 + k) * 512 + n]);
        }
        ((bf16x8*)fragE)[u] = r;
    }
}

// ---------------------------------------------------------------------------
// K1: conv1 MFMA (M=64 px per block, N=64, K=256) + LN(64) + gelu -> s1 bf16
// grid 4096 = bt(1024) x quarter(4).  32 KB LDS -> 4 blocks/CU (full occ).
// Wave owns M-tile mt=wave (output row ohl=wave, 16 ow).  A LDS swizzle
// kq^(pxl&7); B frags (32 KB) stream from L1.
// ---------------------------------------------------------------------------
__global__ __launch_bounds__(256) void k_conv1(
        const float* __restrict__ x, const unsigned short* __restrict__ frag1,
        const float* __restrict__ cb, const float* __restrict__ g,
        const float* __restrict__ bb, unsigned short* __restrict__ s1b) {
    __shared__ unsigned short lds[16384];        // 32 KB

    int blk = blockIdx.x;
    int bt = blk >> 2, q = blk & 3;
    int tid = threadIdx.x, lane = tid & 63;
    int wave = __builtin_amdgcn_readfirstlane(tid >> 6);
    int col = lane & 15, grp = lane >> 4, sw = col & 7;

    // stage x (fp32) -> bf16 LDS: 64 px x 32 kq units (16B)
    const float* xb = x + (size_t)bt * 65536 + (size_t)q * 16384;
    #pragma unroll
    for (int it = 0; it < 8; ++it) {
        int i = it * 256 + tid;                  // 0..2047 (16B units)
        int q8 = i & 7, ow = (i >> 3) & 15, kh = (i >> 7) & 3, ohl = (i >> 9) & 3;
        const float* p = xb + ((ohl * 4 + kh) * 1024 + ow * 64 + q8 * 8);
        float4 v0 = *(const float4*)p;
        float4 v1 = *(const float4*)(p + 4);
        int pxl = ohl * 16 + ow;
        int kq = (kh * 8 + q8) ^ (pxl & 7);
        ((bf16x8*)lds)[pxl * 32 + kq] = pack8(v0, v1);
    }
    __syncthreads();

    f32x4 acc[4];
    #pragma unroll
    for (int n = 0; n < 4; ++n) acc[n] = (f32x4)(0.f);

    const bf16x8* Af = (const bf16x8*)lds;
    const bf16x8* Bf = (const bf16x8*)frag1;
    #pragma unroll
    for (int ki = 0; ki < 8; ++ki) {
        bf16x8 a = Af[(wave * 16 + col) * 32 + ((ki * 4 + grp) ^ sw)];
        #pragma unroll
        for (int nt = 0; nt < 4; ++nt) {
            bf16x8 b = Bf[(nt * 8 + ki) * 64 + lane];
            acc[nt] = MFMA(a, b, acc[nt]);
        }
    }

    // conv bias, LN(64) via 16-lane shuffles
    float cbv[4], gv[4], bv[4];
    #pragma unroll
    for (int nt = 0; nt < 4; ++nt) {
        cbv[nt] = cb[nt * 16 + col];
        gv[nt]  = g[nt * 16 + col];
        bv[nt]  = bb[nt * 16 + col];
    }
    float s[4], ss[4];
    #pragma unroll
    for (int j = 0; j < 4; ++j) { s[j] = 0.f; ss[j] = 0.f; }
    #pragma unroll
    for (int nt = 0; nt < 4; ++nt)
        #pragma unroll
        for (int j = 0; j < 4; ++j) {
            float v = acc[nt][j] + cbv[nt];
            acc[nt][j] = v;
            s[j] += v; ss[j] += v * v;
        }
    #pragma unroll
    for (int j = 0; j < 4; ++j) {
        #pragma unroll
        for (int d = 1; d < 16; d <<= 1) {
            s[j]  += __shfl_xor(s[j], d, 64);
            ss[j] += __shfl_xor(ss[j], d, 64);
        }
        float mm = s[j] * (1.f / 64.f);
        float var = ss[j] * (1.f / 64.f) - mm * mm;
        float rs = rsqrtf(var + 1e-5f);
        int pxl = wave * 16 + grp * 4 + j;       // own-wave row
        #pragma unroll
        for (int nt = 0; nt < 4; ++nt) {
            float y = gelu_exact((acc[nt][j] - mm) * rs * gv[nt] + bv[nt]);
            lds[pxl * 256 + nt * 16 + col] = f2bf(y);   // wave-ordered LDS
        }
    }

    // coalesced bf16 write-out of own rows (oh = q*4+wave, ow = pxl_loc)
    size_t gb = ((size_t)bt * 256 + q * 64 + wave * 16) * 8;   // 16B units
    #pragma unroll
    for (int it = 0; it < 2; ++it) {
        int u = it * 64 + lane;                  // 0..127
        int pxl_loc = u >> 3, cq = u & 7;
        bf16x8 v = ((const bf16x8*)lds)[(wave * 16 + pxl_loc) * 32 + cq];
        ((bf16x8*)s1b)[gb + pxl_loc * 8 + cq] = v;
    }
}

// ---------------------------------------------------------------------------
// K2: conv2 MFMA (M=64 px, N=256, K=1024 in 4 chunks) + LN(256) + gelu
// (unchanged from passing round-4 version)
// ---------------------------------------------------------------------------
__global__ __launch_bounds__(256) void k_conv2(
        const unsigned short* __restrict__ s1b, const unsigned short* __restrict__ frag2,
        const float* __restrict__ cb, const float* __restrict__ g,
        const float* __restrict__ bb, unsigned short* __restrict__ s2b) {
    __shared__ unsigned short lds[16384];        // 32 KB A / epilogue
    __shared__ float sc[512];

    int blk = blockIdx.x;
    int pxg0 = blk * 64;
    int tid = threadIdx.x, lane = tid & 63;
    int wave = __builtin_amdgcn_readfirstlane(tid >> 6);
    int col = lane & 15, grp = lane >> 4, sw = col & 7;

    f32x4 acc[4][4];
    #pragma unroll
    for (int m = 0; m < 4; ++m)
        #pragma unroll
        for (int n = 0; n < 4; ++n) acc[m][n] = (f32x4)(0.f);

    const bf16x8* Af = (const bf16x8*)lds;
    const bf16x8* Bf = (const bf16x8*)frag2;
    int nt0 = wave * 4;

    for (int kc = 0; kc < 4; ++kc) {
        if (kc) __syncthreads();
        #pragma unroll
        for (int it = 0; it < 8; ++it) {
            int i = it * 256 + tid;              // 0..2047
            int pxl = i >> 5, kq = i & 31;
            int pxg = pxg0 + pxl, bt = pxg >> 4, pxi = pxg & 15;
            int row = (pxi >> 2) * 4 + kc, colb = (pxi & 3) * 4;
            bf16x8 v = ((const bf16x8*)s1b)[((size_t)bt * 256 + row * 16 + colb) * 8 + kq];
            ((bf16x8*)lds)[pxl * 32 + (kq ^ (pxl & 7))] = v;
        }
        __syncthreads();
        #pragma unroll
        for (int ki = 0; ki < 8; ++ki) {
            int kk = kc * 8 + ki;
            bf16x8 a[4];
            #pragma unroll
            for (int m = 0; m < 4; ++m)
                a[m] = Af[(m * 16 + col) * 32 + ((ki * 4 + grp) ^ sw)];
            #pragma unroll
            for (int n = 0; n < 4; ++n) {
                bf16x8 b = Bf[((nt0 + n) * 32 + kk) * 64 + lane];
                #pragma unroll
                for (int m = 0; m < 4; ++m)
                    acc[m][n] = MFMA(a[m], b, acc[m][n]);
            }
        }
    }

    float cbv[4], gv[4], bv[4];
    #pragma unroll
    for (int n = 0; n < 4; ++n) {
        cbv[n] = cb[(nt0 + n) * 16 + col];
        gv[n]  = g[(nt0 + n) * 16 + col];
        bv[n]  = bb[(nt0 + n) * 16 + col];
    }
    float s[4][4], ss[4][4];
    #pragma unroll
    for (int m = 0; m < 4; ++m)
        #pragma unroll
        for (int j = 0; j < 4; ++j) { s[m][j] = 0.f; ss[m][j] = 0.f; }
    #pragma unroll
    for (int m = 0; m < 4; ++m)
        #pragma unroll
        for (int n = 0; n < 4; ++n)
            #pragma unroll
            for (int j = 0; j < 4; ++j) {
                float v = acc[m][n][j] + cbv[n];
                acc[m][n][j] = v;
                s[m][j] += v; ss[m][j] += v * v;
            }
    #pragma unroll
    for (int m = 0; m < 4; ++m)
        #pragma unroll
        for (int j = 0; j < 4; ++j) {
            #pragma unroll
            for (int d = 1; d < 16; d <<= 1) {
                s[m][j]  += __shfl_xor(s[m][j], d, 64);
                ss[m][j] += __shfl_xor(ss[m][j], d, 64);
            }
        }
    if (col == 0) {
        #pragma unroll
        for (int m = 0; m < 4; ++m)
            #pragma unroll
            for (int j = 0; j < 4; ++j) {
                int px = m * 16 + grp * 4 + j;
                sc[px * 8 + wave] = s[m][j];
                sc[px * 8 + 4 + wave] = ss[m][j];
            }
    }
    __syncthreads();

    #pragma unroll
    for (int m = 0; m < 4; ++m)
        #pragma unroll
        for (int j = 0; j < 4; ++j) {
            int px = m * 16 + grp * 4 + j;
            float4 Sv  = *(const float4*)&sc[px * 8];
            float4 SSv = *(const float4*)&sc[px * 8 + 4];
            float S  = Sv.x + Sv.y + Sv.z + Sv.w;
            float SS = SSv.x + SSv.y + SSv.z + SSv.w;
            float mm = S * (1.f / 256.f);
            float var = SS * (1.f / 256.f) - mm * mm;
            float rs = rsqrtf(var + 1e-5f);
            #pragma unroll
            for (int n = 0; n < 4; ++n) {
                float y = gelu_exact((acc[m][n][j] - mm) * rs * gv[n] + bv[n]);
                lds[px * 256 + (nt0 + n) * 16 + col] = f2bf(y);
            }
        }
    __syncthreads();

    #pragma unroll
    for (int it = 0; it < 8; ++it) {
        int u = it * 256 + tid;                  // 0..2047
        int pxl = u >> 5, cq = u & 31;
        bf16x8 v = ((const bf16x8*)lds)[pxl * 32 + cq];
        ((bf16x8*)s2b)[((size_t)(pxg0 + pxl)) * 32 + cq] = v;
    }
}

// ---------------------------------------------------------------------------
// K3: fc MFMA partials (M=16 rows, N=512, K-chunk=1024). grid 256 = 64 mb x 4 kc.
// 32 KB LDS; wave owns 8 N-tiles, single M-tile.
// ---------------------------------------------------------------------------
__global__ __launch_bounds__(256) void k_fc(
        const unsigned short* __restrict__ s2b, const unsigned short* __restrict__ fragF,
        float* __restrict__ part) {
    __shared__ unsigned short lds[16384];        // 32 KB A-chunk (16 x 1024 bf16)

    int blk = blockIdx.x;
    int mb = blk >> 2, kc = blk & 3;
    int row0 = mb * 16;
    int tid = threadIdx.x, lane = tid & 63;
    int wave = __builtin_amdgcn_readfirstlane(tid >> 6);
    int col = lane & 15, grp = lane >> 4, sw = col & 7;

    #pragma unroll
    for (int it = 0; it < 8; ++it) {
        int u = it * 256 + tid;                  // 0..2047
        int pxl = u >> 7, kq = u & 127;
        bf16x8 v = ((const bf16x8*)s2b)[(size_t)(row0 + pxl) * 512 + kc * 128 + kq];
        ((bf16x8*)lds)[pxl * 128 + (kq ^ (pxl & 7))] = v;
    }
    __syncthreads();

    f32x4 acc[8];
    #pragma unroll
    for (int n = 0; n < 8; ++n) acc[n] = (f32x4)(0.f);

    const bf16x8* Af = (const bf16x8*)lds;
    const bf16x8* Bf = (const bf16x8*)fragF;
    int nt0 = wave * 8;
    #pragma unroll 4
    for (int ki = 0; ki < 32; ++ki) {
        int kk = kc * 32 + ki;
        bf16x8 a = Af[col * 128 + ((ki * 4 + grp) ^ sw)];
        #pragma unroll
        for (int n = 0; n < 8; ++n) {
            bf16x8 b = Bf[((nt0 + n) * 128 + kk) * 64 + lane];
            acc[n] = MFMA(a, b, acc[n]);
        }
    }

    float* pp = part + (size_t)kc * 524288;
    #pragma unroll
    for (int n = 0; n < 8; ++n)
        #pragma unroll
        for (int j = 0; j < 4; ++j) {
            int row = row0 + grp * 4 + j;
            int co = (nt0 + n) * 16 + col;
            pp[(size_t)row * 512 + co] = acc[n][j];
        }
}

// K3b: sum 4 K-partials + bias -> emb (fp32)
__global__ __launch_bounds__(256) void k_fc_sum(
        const float* __restrict__ part, const float* __restrict__ bias,
        float* __restrict__ emb) {
    int i = blockIdx.x * 256 + threadIdx.x;
    size_t q = (size_t)i * 4;
    float4 s0 = *(const float4*)(part + q);
    float4 s1 = *(const float4*)(part + 524288 + q);
    float4 s2 = *(const float4*)(part + 1048576 + q);
    float4 s3 = *(const float4*)(part + 1572864 + q);
    float4 bv = *(const float4*)(bias + (q & 511));
    float4 r;
    r.x = s0.x + s1.x + s2.x + s3.x + bv.x;
    r.y = s0.y + s1.y + s2.y + s3.y + bv.y;
    r.z = s0.z + s1.z + s2.z + s3.z + bv.z;
    r.w = s0.w + s1.w + s2.w + s3.w + bv.w;
    *(float4*)(emb + q) = r;
}

// ---------------------------------------------------------------------------
// K4: Fourier gating (fp32, unchanged).
// ---------------------------------------------------------------------------
__global__ __launch_bounds__(256) void k_gate(
        const float* __restrict__ emb, const float* __restrict__ wg,
        float* __restrict__ topw, int* __restrict__ topi) {
    __shared__ float ct[128], st[128];
    __shared__ float red[32];

    int b = blockIdx.x, tid = threadIdx.x;
    if (tid < 128) {
        int f = tid >> 4, t = tid & 15;
        int m16 = ((f + 1) * t) & 15;
        float ang = 3.14159265358979323846f * (float)m16 * 0.125f;
        ct[tid] = cosf(ang);
        st[tid] = sinf(ang);
    }
    __syncthreads();

    float ampsum[8] = {0,0,0,0,0,0,0,0};
    #pragma unroll
    for (int dd = 0; dd < 2; ++dd) {
        int d = tid + dd * 256;
        float v[16];
        #pragma unroll
        for (int t = 0; t < 16; ++t)
            v[t] = emb[((size_t)b * 16 + t) * 512 + d];
        #pragma unroll
        for (int f = 0; f < 8; ++f) {
            float re = v[0], im = 0.f;
            #pragma unroll
            for (int t = 1; t < 16; ++t) {
                re += v[t] * ct[f * 16 + t];
                im += v[t] * st[f * 16 + t];
            }
            ampsum[f] += sqrtf(re * re + im * im);
        }
    }
    int lane = tid & 63, wave = tid >> 6;
    #pragma unroll
    for (int f = 0; f < 8; ++f) {
        float sv = ampsum[f];
        #pragma unroll
        for (int d = 1; d < 64; d <<= 1) sv += __shfl_xor(sv, d, 64);
        if (lane == 0) red[wave * 8 + f] = sv;
    }
    __syncthreads();
    if (tid == 0) {
        float wts[6];
        #pragma unroll
        for (int e = 0; e < 6; ++e) wts[e] = 0.f;
        #pragma unroll
        for (int f = 0; f < 8; ++f) {
            float S = (red[f] + red[8 + f] + red[16 + f] + red[24 + f])
                      * (0.25f / 512.0f);
            #pragma unroll
            for (int e = 0; e < 6; ++e) wts[e] += S * wg[f * 6 + e];
        }
        int i1 = 0;
        for (int e = 1; e < 6; ++e) if (wts[e] > wts[i1]) i1 = e;
        int i2 = -1;
        for (int e = 0; e < 6; ++e)
            if (e != i1 && (i2 < 0 || wts[e] > wts[i2])) i2 = e;
        float ex = expf(wts[i2] - wts[i1]);
        float den = 1.0f + ex;
        topw[b * 2] = 1.0f / den;
        topw[b * 2 + 1] = ex / den;
        topi[b * 2] = i1;
        topi[b * 2 + 1] = i2;
    }
}

// ---------------------------------------------------------------------------
// K5: routed experts MFMA (unchanged, passing).
// ---------------------------------------------------------------------------
__global__ __launch_bounds__(256) void k_expert(
        const float* __restrict__ emb, const unsigned short* __restrict__ fragE,
        const float* __restrict__ eb, const float* __restrict__ topw,
        const int* __restrict__ topi, float* __restrict__ out) {
    __shared__ unsigned short lds[8192];         // 16 KB

    int b = blockIdx.x;
    int tid = threadIdx.x, lane = tid & 63;
    int wave = __builtin_amdgcn_readfirstlane(tid >> 6);
    int col = lane & 15, grp = lane >> 4, sw = col & 7;

    #pragma unroll
    for (int it = 0; it < 4; ++it) {
        int i = it * 256 + tid;                  // 0..1023
        int pxl = i >> 6, kq = i & 63;
        const float* p = emb + ((size_t)b * 16 + pxl) * 512 + kq * 8;
        float4 v0 = *(const float4*)p;
        float4 v1 = *(const float4*)(p + 4);
        ((bf16x8*)lds)[pxl * 64 + (kq ^ (pxl & 7))] = pack8(v0, v1);
    }
    int e1 = topi[b * 2], e2 = topi[b * 2 + 1];
    float g1 = topw[b * 2], g2 = topw[b * 2 + 1];
    __syncthreads();

    f32x4 acc[2][8];
    #pragma unroll
    for (int m = 0; m < 2; ++m)
        #pragma unroll
        for (int n = 0; n < 8; ++n) acc[m][n] = (f32x4)(0.f);

    const bf16x8* Af = (const bf16x8*)lds;
    const bf16x8* Bf = (const bf16x8*)fragE;
    int nt0 = wave * 8;
    #pragma unroll 4
    for (int ki = 0; ki < 16; ++ki) {
        bf16x8 a = Af[col * 64 + ((ki * 4 + grp) ^ sw)];
        #pragma unroll
        for (int n = 0; n < 8; ++n) {
            bf16x8 b1 = Bf[((size_t)(e1 * 512 + (nt0 + n) * 16 + ki)) * 64 + lane];
            bf16x8 b2 = Bf[((size_t)(e2 * 512 + (nt0 + n) * 16 + ki)) * 64 + lane];
            acc[0][n] = MFMA(a, b1, acc[0][n]);
            acc[1][n] = MFMA(a, b2, acc[1][n]);
        }
    }

    #pragma unroll
    for (int n = 0; n < 8; ++n) {
        int co = (nt0 + n) * 16 + col;
        float b1v = eb[e1 * 512 + co], b2v = eb[e2 * 512 + co];
        #pragma unroll
        for (int j = 0; j < 4; ++j) {
            int row = grp * 4 + j;
            float c = g1 * expf(acc[0][n][j] + b1v) + g2 * expf(acc[1][n][j] + b2v);
            if (c == 0.f) c = EPS_;
            out[((size_t)b * 16 + row) * 512 + co] = logf(c);
        }
    }
}

// ---------------------------------------------------------------------------
extern "C" void kernel_launch(void* const* d_in, const int* in_sizes, int n_in,
                              void* d_out, int out_size, void* d_ws, size_t ws_size,
                              hipStream_t stream) {
    (void)in_sizes; (void)n_in; (void)out_size; (void)ws_size;
    const float* x   = (const float*)d_in[0];
    const float* c1w = (const float*)d_in[1];
    const float* c1b = (const float*)d_in[2];
    const float* l1g = (const float*)d_in[3];
    const float* l1b = (const float*)d_in[4];
    const float* c2w = (const float*)d_in[5];
    const float* c2b = (const float*)d_in[6];
    const float* l2g = (const float*)d_in[7];
    const float* l2b = (const float*)d_in[8];
    const float* fcw = (const float*)d_in[9];
    const float* fcb = (const float*)d_in[10];
    const float* wg  = (const float*)d_in[11];
    const float* ew  = (const float*)d_in[12];
    const float* eb  = (const float*)d_in[13];
    float* out = (float*)d_out;

    unsigned short* wsu  = (unsigned short*)d_ws;
    unsigned short* frag1 = wsu;                    // 16384
    unsigned short* frag2 = frag1 + 16384;          // 262144 used (pad 524288)
    unsigned short* fragF = frag2 + 524288;         // 2097152
    unsigned short* fragE = fragF + 2097152;        // 1572864
    unsigned short* s1b   = fragE + 1572864;        // 16777216
    unsigned short* s2b   = s1b + 16777216;         // 4194304
    float* emb  = (float*)(s2b + 4194304);          // 524288 fp32
    float* part = emb + 524288;                     // 2097152 fp32
    float* topw = part + 2097152;                   // 128
    int*   topi = (int*)(topw + 128);               // 128

    hipLaunchKernelGGL(k_prep, dim3(1928), dim3(256), 0, stream,
                       c1w, c2w, fcw, ew, frag1, frag2, fragF, fragE);
    hipLaunchKernelGGL(k_conv1, dim3(4096), dim3(256), 0, stream,
                       x, frag1, c1b, l1g, l1b, s1b);
    hipLaunchKernelGGL(k_conv2, dim3(256), dim3(256), 0, stream,
                       s1b, frag2, c2b, l2g, l2b, s2b);
    hipLaunchKernelGGL(k_fc, dim3(256), dim3(256), 0, stream, s2b, fragF, part);
    hipLaunchKernelGGL(k_fc_sum, dim3(512), dim3(256), 0, stream, part, fcb, emb);
    hipLaunchKernelGGL(k_gate, dim3(64), dim3(256), 0, stream, emb, wg, topw, topi);
    hipLaunchKernelGGL(k_expert, dim3(64), dim3(256), 0, stream,
                       emb, fragE, eb, topw, topi, out);
}